// Round 1
// baseline (436.692 us; speedup 1.0000x reference)
//
#include <hip/hip_runtime.h>
#include <math.h>

#define SELU_SCALE 1.0507009873554804934193349852946f
#define SELU_ALPHA 1.6732632423543772848170429916717f

__device__ __forceinline__ float selu_f(float x) {
    return SELU_SCALE * (x > 0.f ? x : SELU_ALPHA * expm1f(x));
}

// ---------------------------------------------------------------------------
// K1: local covariance (window 25, divisor 23) + [x,cov] @ w_e1 + b_e1, selu
// one thread per point
// ---------------------------------------------------------------------------
__global__ __launch_bounds__(256) void cov_enc_kernel(
    const float* __restrict__ x, const float* __restrict__ w_e1,
    const float* __restrict__ b_e1, float* __restrict__ h1, int BN) {
    __shared__ float Wl[12 * 64];
    __shared__ float Bl[64];
    int t = threadIdx.x;
    for (int i = t; i < 768; i += 256) Wl[i] = w_e1[i];
    if (t < 64) Bl[t] = b_e1[t];
    __syncthreads();
    int p = blockIdx.x * 256 + t;
    if (p >= BN) return;
    int n = p & 4095;
    const float* xb = x + (size_t)(p - n) * 3;  // batch base
    int lo = n - 12 < 0 ? 0 : n - 12;
    int hi = n + 12 > 4095 ? 4095 : n + 12;
    float sx = 0.f, sy = 0.f, sz = 0.f;
    for (int idx = lo; idx <= hi; idx++) {
        sx += xb[idx * 3 + 0];
        sy += xb[idx * 3 + 1];
        sz += xb[idx * 3 + 2];
    }
    float cntf = (float)(hi - lo + 1);
    float mx = sx / cntf, my = sy / cntf, mz = sz / cntf;
    float c00 = 0.f, c01 = 0.f, c02 = 0.f, c11 = 0.f, c12 = 0.f, c22 = 0.f;
    for (int idx = lo; idx <= hi; idx++) {
        float dx = xb[idx * 3 + 0] - mx;
        float dy = xb[idx * 3 + 1] - my;
        float dz = xb[idx * 3 + 2] - mz;
        c00 = fmaf(dx, dx, c00); c01 = fmaf(dx, dy, c01); c02 = fmaf(dx, dz, c02);
        c11 = fmaf(dy, dy, c11); c12 = fmaf(dy, dz, c12); c22 = fmaf(dz, dz, c22);
    }
    const float inv23 = 1.f / 23.f;
    float feat[12];
    feat[0] = xb[n * 3 + 0]; feat[1] = xb[n * 3 + 1]; feat[2] = xb[n * 3 + 2];
    feat[3] = c00 * inv23; feat[4] = c01 * inv23; feat[5]  = c02 * inv23;
    feat[6] = c01 * inv23; feat[7] = c11 * inv23; feat[8]  = c12 * inv23;
    feat[9] = c02 * inv23; feat[10] = c12 * inv23; feat[11] = c22 * inv23;
    float* hp = h1 + (size_t)p * 64;
    for (int c = 0; c < 64; c++) {
        float acc = Bl[c];
        #pragma unroll
        for (int i = 0; i < 12; i++) acc = fmaf(feat[i], Wl[i * 64 + c], acc);
        hp[c] = selu_f(acc);
    }
}

// ---------------------------------------------------------------------------
// Graph prep: zero, count, scan, dinv, scatter (CSR by dst)
// ---------------------------------------------------------------------------
__global__ void zero2_kernel(int* __restrict__ a, int* __restrict__ b, int n) {
    int i = blockIdx.x * blockDim.x + threadIdx.x;
    if (i < n) { a[i] = 0; b[i] = 0; }
}

__global__ void count_kernel(const int* __restrict__ dst, int* __restrict__ cnt, int E) {
    int e = blockIdx.x * blockDim.x + threadIdx.x;
    if (e < E) atomicAdd(&cnt[dst[e]], 1);
}

__global__ __launch_bounds__(1024) void scan_kernel(
    const int* __restrict__ cnt, int* __restrict__ indptr, int n) {
    // n == 32768, one block of 1024 threads, 32 elems per thread
    __shared__ int sums[1024];
    int t = threadIdx.x;
    int base = t * 32;
    int local[32];
    int s = 0;
    #pragma unroll
    for (int i = 0; i < 32; i++) { local[i] = s; s += cnt[base + i]; }
    sums[t] = s;
    __syncthreads();
    for (int off = 1; off < 1024; off <<= 1) {
        int v = (t >= off) ? sums[t - off] : 0;
        __syncthreads();
        sums[t] += v;
        __syncthreads();
    }
    int off = sums[t] - s;  // exclusive prefix for this chunk
    #pragma unroll
    for (int i = 0; i < 32; i++) indptr[base + i] = off + local[i];
    if (t == 1023) indptr[n] = sums[1023];
}

__global__ void dinv_kernel(const int* __restrict__ cnt, float* __restrict__ dinv, int n) {
    int i = blockIdx.x * blockDim.x + threadIdx.x;
    if (i < n) dinv[i] = rsqrtf((float)(cnt[i] + 1));  // +1 self-loop
}

__global__ void scatter_kernel(const int* __restrict__ src, const int* __restrict__ dst,
                               const int* __restrict__ indptr, int* __restrict__ cursor,
                               int* __restrict__ ssrc, int E) {
    int e = blockIdx.x * blockDim.x + threadIdx.x;
    if (e < E) {
        int d = dst[e];
        int pos = atomicAdd(&cursor[d], 1);
        ssrc[indptr[d] + pos] = src[e];
    }
}

// ---------------------------------------------------------------------------
// Aggregation: out[d] = dinv[d] * ( sum_{s in N(d)} dinv[s]*h[s] + dinv[d]*h[d] )
// C channels per node, 256/C nodes per block; each wave uniform per node
// ---------------------------------------------------------------------------
template <int C>
__global__ __launch_bounds__(256) void agg_kernel(
    const float* __restrict__ h, const float* __restrict__ dinv,
    const int* __restrict__ indptr, const int* __restrict__ ssrc,
    float* __restrict__ out, int n_nodes) {
    int node = blockIdx.x * (256 / C) + threadIdx.x / C;
    int c = threadIdx.x % C;
    if (node >= n_nodes) return;
    float dv = dinv[node];
    float acc = dv * h[(size_t)node * C + c];
    int beg = indptr[node], end = indptr[node + 1];
    for (int j = beg; j < end; ++j) {
        int s = ssrc[j];
        acc = fmaf(dinv[s], h[(size_t)s * C + c], acc);
    }
    out[(size_t)node * C + c] = dv * acc;
}

// ---------------------------------------------------------------------------
// Register-blocked f32 GEMM: out = selu(A[M,KTOT] @ W[KTOT,Nfull] + bias)
// tile 64 rows x 128 cols, K chunks of 64, thread = 4x8 outputs
// POOL=true: instead of storing rows, store per-tile column max -> pmax
// ---------------------------------------------------------------------------
template <int KTOT, bool POOL>
__global__ __launch_bounds__(256) void gemm_kernel(
    const float* __restrict__ A, const float* __restrict__ W,
    const float* __restrict__ bias, float* __restrict__ out, int Nfull) {
    __shared__ float As[64 * 65];   // A^T [k][r], stride 65
    __shared__ float Ws[64 * 128];  // W   [k][c]
    int t = threadIdx.x;
    int R0 = blockIdx.x * 64;
    int cb = blockIdx.y * 128;
    int r0 = (t >> 4) * 4;
    int c0 = (t & 15) * 8;
    float acc[4][8];
    #pragma unroll
    for (int i = 0; i < 4; i++)
        #pragma unroll
        for (int j = 0; j < 8; j++) acc[i][j] = 0.f;

    for (int k0 = 0; k0 < KTOT; k0 += 64) {
        #pragma unroll
        for (int q = 0; q < 4; q++) {
            int id = t + q * 256;  // 1024 float4s = 64x64 floats
            int r = id >> 4;
            int k4 = id & 15;
            float4 v = *(const float4*)&A[(size_t)(R0 + r) * KTOT + k0 + k4 * 4];
            As[(k4 * 4 + 0) * 65 + r] = v.x;
            As[(k4 * 4 + 1) * 65 + r] = v.y;
            As[(k4 * 4 + 2) * 65 + r] = v.z;
            As[(k4 * 4 + 3) * 65 + r] = v.w;
        }
        #pragma unroll
        for (int q = 0; q < 8; q++) {
            int id = t + q * 256;  // 2048 float4s = 64x128 floats
            int kr = id >> 5;
            int c4 = id & 31;
            *(float4*)&Ws[kr * 128 + c4 * 4] =
                *(const float4*)&W[(size_t)(k0 + kr) * Nfull + cb + c4 * 4];
        }
        __syncthreads();
        #pragma unroll 16
        for (int k = 0; k < 64; k++) {
            float a0 = As[k * 65 + r0 + 0];
            float a1 = As[k * 65 + r0 + 1];
            float a2 = As[k * 65 + r0 + 2];
            float a3 = As[k * 65 + r0 + 3];
            float4 b0 = *(const float4*)&Ws[k * 128 + c0];
            float4 b1 = *(const float4*)&Ws[k * 128 + c0 + 4];
            float bb[8] = {b0.x, b0.y, b0.z, b0.w, b1.x, b1.y, b1.z, b1.w};
            #pragma unroll
            for (int j = 0; j < 8; j++) {
                acc[0][j] = fmaf(a0, bb[j], acc[0][j]);
                acc[1][j] = fmaf(a1, bb[j], acc[1][j]);
                acc[2][j] = fmaf(a2, bb[j], acc[2][j]);
                acc[3][j] = fmaf(a3, bb[j], acc[3][j]);
            }
        }
        __syncthreads();
    }

    if (POOL) {
        float cmax[8];
        #pragma unroll
        for (int j = 0; j < 8; j++) {
            float bj = bias[cb + c0 + j];
            float mj = -INFINITY;
            #pragma unroll
            for (int i = 0; i < 4; i++) mj = fmaxf(mj, selu_f(acc[i][j] + bj));
            cmax[j] = mj;
        }
        float* red = As;  // reuse: [16][128]
        #pragma unroll
        for (int j = 0; j < 8; j++) red[(t >> 4) * 128 + c0 + j] = cmax[j];
        __syncthreads();
        if (t < 128) {
            float mv = -INFINITY;
            #pragma unroll
            for (int g = 0; g < 16; g++) mv = fmaxf(mv, red[g * 128 + t]);
            out[(size_t)blockIdx.x * Nfull + cb + t] = mv;  // pmax[tile][col]
        }
    } else {
        #pragma unroll
        for (int i = 0; i < 4; i++) {
            float4 o0, o1;
            o0.x = selu_f(acc[i][0] + bias[cb + c0 + 0]);
            o0.y = selu_f(acc[i][1] + bias[cb + c0 + 1]);
            o0.z = selu_f(acc[i][2] + bias[cb + c0 + 2]);
            o0.w = selu_f(acc[i][3] + bias[cb + c0 + 3]);
            o1.x = selu_f(acc[i][4] + bias[cb + c0 + 4]);
            o1.y = selu_f(acc[i][5] + bias[cb + c0 + 5]);
            o1.z = selu_f(acc[i][6] + bias[cb + c0 + 6]);
            o1.w = selu_f(acc[i][7] + bias[cb + c0 + 7]);
            *(float4*)&out[(size_t)(R0 + r0 + i) * Nfull + cb + c0] = o0;
            *(float4*)&out[(size_t)(R0 + r0 + i) * Nfull + cb + c0 + 4] = o1;
        }
    }
}

// ---------------------------------------------------------------------------
// reduce pmax tiles (64 per batch) -> m[b][512]
// ---------------------------------------------------------------------------
__global__ void maxreduce_kernel(const float* __restrict__ pmax, float* __restrict__ m,
                                 int total) {
    int idx = blockIdx.x * blockDim.x + threadIdx.x;  // b*512 + c
    if (idx >= total) return;
    int b = idx >> 9;
    int c = idx & 511;
    const float* p = pmax + (size_t)(b * 64) * 512 + c;
    float v = -INFINITY;
    for (int tIdx = 0; tIdx < 64; tIdx++) v = fmaxf(v, p[tIdx * 512]);
    m[idx] = v;
}

// ---------------------------------------------------------------------------
// lat = selu(m @ w_e2 + b_e2); latw1 = lat @ w_d1[:512] + b_d1;
// latw2 = lat @ w_d2[:512] + b_d2.  One block per batch.
// ---------------------------------------------------------------------------
__global__ __launch_bounds__(256) void lat_kernel(
    const float* __restrict__ m, const float* __restrict__ w_e2,
    const float* __restrict__ b_e2, const float* __restrict__ w_d1,
    const float* __restrict__ b_d1, const float* __restrict__ w_d2,
    const float* __restrict__ b_d2, float* __restrict__ latw1,
    float* __restrict__ latw2) {
    int b = blockIdx.x;
    int t = threadIdx.x;
    __shared__ float ml[512], ll[512];
    __shared__ float red[6][256];
    ml[t] = m[b * 512 + t];
    ml[t + 256] = m[b * 512 + t + 256];
    __syncthreads();
    for (int cc = 0; cc < 2; cc++) {
        int c = t + cc * 256;
        float acc = b_e2[c];
        for (int k = 0; k < 512; k++) acc = fmaf(ml[k], w_e2[k * 512 + c], acc);
        ll[c] = selu_f(acc);
    }
    __syncthreads();
    float p[6] = {0.f, 0.f, 0.f, 0.f, 0.f, 0.f};
    for (int k = t; k < 512; k += 256) {
        float lv = ll[k];
        #pragma unroll
        for (int j = 0; j < 3; j++) {
            p[j]     = fmaf(lv, w_d1[k * 3 + j], p[j]);
            p[3 + j] = fmaf(lv, w_d2[k * 3 + j], p[3 + j]);
        }
    }
    #pragma unroll
    for (int j = 0; j < 6; j++) red[j][t] = p[j];
    __syncthreads();
    for (int s = 128; s > 0; s >>= 1) {
        if (t < s) {
            #pragma unroll
            for (int j = 0; j < 6; j++) red[j][t] += red[j][t + s];
        }
        __syncthreads();
    }
    if (t < 3) {
        latw1[b * 3 + t] = red[t][0] + b_d1[t];
        latw2[b * 3 + t] = red[3 + t][0] + b_d2[t];
    }
}

// ---------------------------------------------------------------------------
// decoder: per point, grid coords + two 3-wide folds
// ---------------------------------------------------------------------------
__global__ void decode_kernel(const float* __restrict__ latw1, const float* __restrict__ latw2,
                              const float* __restrict__ w_d1, const float* __restrict__ w_d2,
                              float* __restrict__ out, int total) {
    int p = blockIdx.x * blockDim.x + threadIdx.x;
    if (p >= total) return;
    int b = p >> 12;
    int n = p & 4095;
    int i = n / 46;
    int j = n - i * 46;
    float y0 = fmaf((float)i, 119.f / 90.f, 1.f);
    float y1 = fmaf((float)j, 59.f / 45.f, 1.f);
    float k0 = selu_f(latw1[b * 3 + 0] + y0 * w_d1[1536 + 0] + y1 * w_d1[1539 + 0]);
    float k1 = selu_f(latw1[b * 3 + 1] + y0 * w_d1[1536 + 1] + y1 * w_d1[1539 + 1]);
    float k2 = selu_f(latw1[b * 3 + 2] + y0 * w_d1[1539 - 3 + 2] + y1 * w_d1[1539 + 2]);
    // (w_d1 row 512 = idx 1536.., row 513 = idx 1539..)
    float o0 = selu_f(latw2[b * 3 + 0] + k0 * w_d2[1536 + 0] + k1 * w_d2[1539 + 0] + k2 * w_d2[1542 + 0]);
    float o1 = selu_f(latw2[b * 3 + 1] + k0 * w_d2[1536 + 1] + k1 * w_d2[1539 + 1] + k2 * w_d2[1542 + 1]);
    float o2 = selu_f(latw2[b * 3 + 2] + k0 * w_d2[1536 + 2] + k1 * w_d2[1539 + 2] + k2 * w_d2[1542 + 2]);
    out[(size_t)p * 3 + 0] = o0;
    out[(size_t)p * 3 + 1] = o1;
    out[(size_t)p * 3 + 2] = o2;
}

// ---------------------------------------------------------------------------
extern "C" void kernel_launch(void* const* d_in, const int* in_sizes, int n_in,
                              void* d_out, int out_size, void* d_ws, size_t ws_size,
                              hipStream_t stream) {
    const float* x    = (const float*)d_in[0];
    const int*   knn  = (const int*)d_in[1];
    const float* w_e1 = (const float*)d_in[2];
    const float* b_e1 = (const float*)d_in[3];
    const float* w_g1 = (const float*)d_in[4];
    const float* b_g1 = (const float*)d_in[5];
    const float* w_g2 = (const float*)d_in[6];
    const float* b_g2 = (const float*)d_in[7];
    const float* w_e2 = (const float*)d_in[8];
    const float* b_e2 = (const float*)d_in[9];
    const float* w_d1 = (const float*)d_in[10];
    const float* b_d1 = (const float*)d_in[11];
    const float* w_d2 = (const float*)d_in[12];
    const float* b_d2 = (const float*)d_in[13];
    float* out = (float*)d_out;

    const int BN = in_sizes[0] / 3;   // 32768
    const int E  = in_sizes[1] / 2;   // 524288
    const int Bb = BN / 4096;         // 8
    const int* src = knn;
    const int* dst = knn + E;

    size_t off = 0;
    auto alloc = [&](size_t bytes) -> void* {
        void* p = (char*)d_ws + off;
        off += (bytes + 255) & ~(size_t)255;
        return p;
    };
    float* h1     = (float*)alloc((size_t)BN * 64 * 4);
    float* a1     = (float*)alloc((size_t)BN * 64 * 4);
    float* h2     = (float*)alloc((size_t)BN * 128 * 4);
    float* a2     = (float*)alloc((size_t)BN * 128 * 4);
    float* pmax   = (float*)alloc((size_t)(BN / 64) * 512 * 4);
    float* m      = (float*)alloc((size_t)Bb * 512 * 4);
    float* latw1  = (float*)alloc((size_t)Bb * 3 * 4);
    float* latw2  = (float*)alloc((size_t)Bb * 3 * 4);
    float* dinv   = (float*)alloc((size_t)BN * 4);
    int*   cnt    = (int*)alloc((size_t)BN * 4);
    int*   cursor = (int*)alloc((size_t)BN * 4);
    int*   indptr = (int*)alloc((size_t)(BN + 1) * 4);
    int*   ssrc   = (int*)alloc((size_t)E * 4);
    (void)ws_size;

    // graph prep
    zero2_kernel<<<(BN + 255) / 256, 256, 0, stream>>>(cnt, cursor, BN);
    count_kernel<<<(E + 255) / 256, 256, 0, stream>>>(dst, cnt, E);
    scan_kernel<<<1, 1024, 0, stream>>>(cnt, indptr, BN);
    dinv_kernel<<<(BN + 255) / 256, 256, 0, stream>>>(cnt, dinv, BN);
    scatter_kernel<<<(E + 255) / 256, 256, 0, stream>>>(src, dst, indptr, cursor, ssrc, E);

    // encoder
    cov_enc_kernel<<<(BN + 255) / 256, 256, 0, stream>>>(x, w_e1, b_e1, h1, BN);

    // GCN1: aggregate(64) -> gemm 64x128 + selu
    agg_kernel<64><<<BN / 4, 256, 0, stream>>>(h1, dinv, indptr, ssrc, a1, BN);
    gemm_kernel<64, false><<<dim3(BN / 64, 1), 256, 0, stream>>>(a1, w_g1, b_g1, h2, 128);

    // GCN2: aggregate(128) -> gemm 128x512 + selu + fused column-max
    agg_kernel<128><<<BN / 2, 256, 0, stream>>>(h2, dinv, indptr, ssrc, a2, BN);
    gemm_kernel<128, true><<<dim3(BN / 64, 4), 256, 0, stream>>>(a2, w_g2, b_g2, pmax, 512);

    // max-pool finalize + latent + per-batch decoder coefficients
    maxreduce_kernel<<<(Bb * 512 + 255) / 256, 256, 0, stream>>>(pmax, m, Bb * 512);
    lat_kernel<<<Bb, 256, 0, stream>>>(m, w_e2, b_e2, w_d1, b_d1, w_d2, b_d2, latw1, latw2);

    // decoder
    decode_kernel<<<(BN + 255) / 256, 256, 0, stream>>>(latw1, latw2, w_d1, w_d2, out, BN);
}

// Round 2
// 336.797 us; speedup vs baseline: 1.2966x; 1.2966x over previous
//
#include <hip/hip_runtime.h>
#include <math.h>

#define SELU_SCALE 1.0507009873554804934193349852946f
#define SELU_ALPHA 1.6732632423543772848170429916717f

__device__ __forceinline__ float selu_f(float x) {
    return SELU_SCALE * (x > 0.f ? x : SELU_ALPHA * expm1f(x));
}

__device__ __forceinline__ unsigned short f2bf(float f) {
    unsigned int u = __float_as_uint(f);
    u += 0x7FFF + ((u >> 16) & 1);  // round-to-nearest-even
    return (unsigned short)(u >> 16);
}
__device__ __forceinline__ float bflo(unsigned int u) { return __uint_as_float(u << 16); }
__device__ __forceinline__ float bfhi(unsigned int u) { return __uint_as_float(u & 0xFFFF0000u); }

// ---------------------------------------------------------------------------
// K1: local covariance (window 25, divisor 23) + [x,cov] @ w_e1 + b_e1, selu,
// prescaled by dinv[p], stored bf16.  One thread per point.
// ---------------------------------------------------------------------------
__global__ __launch_bounds__(256) void cov_enc_kernel(
    const float* __restrict__ x, const float* __restrict__ w_e1,
    const float* __restrict__ b_e1, const float* __restrict__ dinv,
    unsigned short* __restrict__ hs1, int BN) {
    __shared__ float Wl[12 * 64];
    __shared__ float Bl[64];
    int t = threadIdx.x;
    for (int i = t; i < 768; i += 256) Wl[i] = w_e1[i];
    if (t < 64) Bl[t] = b_e1[t];
    __syncthreads();
    int p = blockIdx.x * 256 + t;
    if (p >= BN) return;
    int n = p & 4095;
    const float* xb = x + (size_t)(p - n) * 3;  // batch base
    int lo = n - 12 < 0 ? 0 : n - 12;
    int hi = n + 12 > 4095 ? 4095 : n + 12;
    float sx = 0.f, sy = 0.f, sz = 0.f;
    for (int idx = lo; idx <= hi; idx++) {
        sx += xb[idx * 3 + 0];
        sy += xb[idx * 3 + 1];
        sz += xb[idx * 3 + 2];
    }
    float cntf = (float)(hi - lo + 1);
    float mx = sx / cntf, my = sy / cntf, mz = sz / cntf;
    float c00 = 0.f, c01 = 0.f, c02 = 0.f, c11 = 0.f, c12 = 0.f, c22 = 0.f;
    for (int idx = lo; idx <= hi; idx++) {
        float dx = xb[idx * 3 + 0] - mx;
        float dy = xb[idx * 3 + 1] - my;
        float dz = xb[idx * 3 + 2] - mz;
        c00 = fmaf(dx, dx, c00); c01 = fmaf(dx, dy, c01); c02 = fmaf(dx, dz, c02);
        c11 = fmaf(dy, dy, c11); c12 = fmaf(dy, dz, c12); c22 = fmaf(dz, dz, c22);
    }
    const float inv23 = 1.f / 23.f;
    float feat[12];
    feat[0] = xb[n * 3 + 0]; feat[1] = xb[n * 3 + 1]; feat[2] = xb[n * 3 + 2];
    feat[3] = c00 * inv23; feat[4] = c01 * inv23; feat[5]  = c02 * inv23;
    feat[6] = c01 * inv23; feat[7] = c11 * inv23; feat[8]  = c12 * inv23;
    feat[9] = c02 * inv23; feat[10] = c12 * inv23; feat[11] = c22 * inv23;
    float dv = dinv[p];
    unsigned int* hp = (unsigned int*)(hs1 + (size_t)p * 64);
    for (int c = 0; c < 64; c += 2) {
        float a0 = Bl[c], a1 = Bl[c + 1];
        #pragma unroll
        for (int i = 0; i < 12; i++) {
            a0 = fmaf(feat[i], Wl[i * 64 + c], a0);
            a1 = fmaf(feat[i], Wl[i * 64 + c + 1], a1);
        }
        unsigned int pk = (unsigned int)f2bf(dv * selu_f(a0)) |
                          ((unsigned int)f2bf(dv * selu_f(a1)) << 16);
        hp[c >> 1] = pk;
    }
}

// ---------------------------------------------------------------------------
// Graph prep: zero, count, scan, dinv, scatter (CSR by dst)
// ---------------------------------------------------------------------------
__global__ void zero2_kernel(int* __restrict__ a, int* __restrict__ b, int n) {
    int i = blockIdx.x * blockDim.x + threadIdx.x;
    if (i < n) { a[i] = 0; b[i] = 0; }
}

__global__ void count_kernel(const int* __restrict__ dst, int* __restrict__ cnt, int E) {
    int e = blockIdx.x * blockDim.x + threadIdx.x;
    if (e < E) atomicAdd(&cnt[dst[e]], 1);
}

__global__ __launch_bounds__(1024) void scan_kernel(
    const int* __restrict__ cnt, int* __restrict__ indptr, int n) {
    // n == 32768, one block of 1024 threads, 32 elems per thread
    __shared__ int sums[1024];
    int t = threadIdx.x;
    int base = t * 32;
    int local[32];
    int s = 0;
    #pragma unroll
    for (int i = 0; i < 32; i++) { local[i] = s; s += cnt[base + i]; }
    sums[t] = s;
    __syncthreads();
    for (int off = 1; off < 1024; off <<= 1) {
        int v = (t >= off) ? sums[t - off] : 0;
        __syncthreads();
        sums[t] += v;
        __syncthreads();
    }
    int off = sums[t] - s;  // exclusive prefix for this chunk
    #pragma unroll
    for (int i = 0; i < 32; i++) indptr[base + i] = off + local[i];
    if (t == 1023) indptr[n] = sums[1023];
}

__global__ void dinv_kernel(const int* __restrict__ cnt, float* __restrict__ dinv, int n) {
    int i = blockIdx.x * blockDim.x + threadIdx.x;
    if (i < n) dinv[i] = rsqrtf((float)(cnt[i] + 1));  // +1 self-loop
}

__global__ void scatter_kernel(const int* __restrict__ src, const int* __restrict__ dst,
                               const int* __restrict__ indptr, int* __restrict__ cursor,
                               int* __restrict__ ssrc, int E) {
    int e = blockIdx.x * blockDim.x + threadIdx.x;
    if (e < E) {
        int d = dst[e];
        int pos = atomicAdd(&cursor[d], 1);
        ssrc[indptr[d] + pos] = src[e];
    }
}

// ---------------------------------------------------------------------------
// Aggregation: out[d] = dinv[d] * ( hs[d] + sum_{s in N(d)} hs[s] )  where
// hs = dinv .* h (prescaled bf16).  2 channels per thread (uint gather).
// Neighbor loop batched 8-deep to keep 8 loads in flight per thread.
// ---------------------------------------------------------------------------
template <int C>
__global__ __launch_bounds__(256) void agg_kernel(
    const unsigned short* __restrict__ hs, const float* __restrict__ dinv,
    const int* __restrict__ indptr, const int* __restrict__ ssrc,
    float* __restrict__ out, int n_nodes) {
    constexpr int TPN = C / 2;  // threads per node
    int node = blockIdx.x * (256 / TPN) + threadIdx.x / TPN;
    int cp = threadIdx.x % TPN;  // channel pair
    if (node >= n_nodes) return;
    const unsigned int* hsp = (const unsigned int*)hs;
    unsigned int u = hsp[(size_t)node * TPN + cp];
    float a0 = bflo(u), a1 = bfhi(u);
    int beg = indptr[node], end = indptr[node + 1];
    int j = beg;
    for (; j + 8 <= end; j += 8) {
        int s[8];
        #pragma unroll
        for (int q = 0; q < 8; q++) s[q] = ssrc[j + q];
        unsigned int v[8];
        #pragma unroll
        for (int q = 0; q < 8; q++) v[q] = hsp[(size_t)s[q] * TPN + cp];
        #pragma unroll
        for (int q = 0; q < 8; q++) { a0 += bflo(v[q]); a1 += bfhi(v[q]); }
    }
    for (; j < end; j++) {
        unsigned int v = hsp[(size_t)ssrc[j] * TPN + cp];
        a0 += bflo(v); a1 += bfhi(v);
    }
    float dv = dinv[node];
    float2 o;
    o.x = a0 * dv;
    o.y = a1 * dv;
    *(float2*)&out[(size_t)node * C + cp * 2] = o;
}

// ---------------------------------------------------------------------------
// Register-blocked f32 GEMM: tile 64 rows x 128 cols, K chunks of 64,
// thread = 4x8 outputs.
// MODE 0: store f32 rows (selu)          -> outf
// MODE 1: per-tile column max (selu)     -> outf (pmax)
// MODE 2: store bf16 rows dinv*selu(...) -> outh
// ---------------------------------------------------------------------------
template <int KTOT, int MODE>
__global__ __launch_bounds__(256) void gemm_kernel(
    const float* __restrict__ A, const float* __restrict__ W,
    const float* __restrict__ bias, float* __restrict__ outf,
    unsigned short* __restrict__ outh, const float* __restrict__ dinv,
    int Nfull) {
    __shared__ float As[64 * 65];   // A^T [k][r], stride 65
    __shared__ float Ws[64 * 128];  // W   [k][c]
    int t = threadIdx.x;
    int R0 = blockIdx.x * 64;
    int cb = blockIdx.y * 128;
    int r0 = (t >> 4) * 4;
    int c0 = (t & 15) * 8;
    float acc[4][8];
    #pragma unroll
    for (int i = 0; i < 4; i++)
        #pragma unroll
        for (int j = 0; j < 8; j++) acc[i][j] = 0.f;

    for (int k0 = 0; k0 < KTOT; k0 += 64) {
        #pragma unroll
        for (int q = 0; q < 4; q++) {
            int id = t + q * 256;  // 1024 float4s = 64x64 floats
            int r = id >> 4;
            int k4 = id & 15;
            float4 v = *(const float4*)&A[(size_t)(R0 + r) * KTOT + k0 + k4 * 4];
            As[(k4 * 4 + 0) * 65 + r] = v.x;
            As[(k4 * 4 + 1) * 65 + r] = v.y;
            As[(k4 * 4 + 2) * 65 + r] = v.z;
            As[(k4 * 4 + 3) * 65 + r] = v.w;
        }
        #pragma unroll
        for (int q = 0; q < 8; q++) {
            int id = t + q * 256;  // 2048 float4s = 64x128 floats
            int kr = id >> 5;
            int c4 = id & 31;
            *(float4*)&Ws[kr * 128 + c4 * 4] =
                *(const float4*)&W[(size_t)(k0 + kr) * Nfull + cb + c4 * 4];
        }
        __syncthreads();
        #pragma unroll 16
        for (int k = 0; k < 64; k++) {
            float a0 = As[k * 65 + r0 + 0];
            float a1 = As[k * 65 + r0 + 1];
            float a2 = As[k * 65 + r0 + 2];
            float a3 = As[k * 65 + r0 + 3];
            float4 b0 = *(const float4*)&Ws[k * 128 + c0];
            float4 b1 = *(const float4*)&Ws[k * 128 + c0 + 4];
            float bb[8] = {b0.x, b0.y, b0.z, b0.w, b1.x, b1.y, b1.z, b1.w};
            #pragma unroll
            for (int j = 0; j < 8; j++) {
                acc[0][j] = fmaf(a0, bb[j], acc[0][j]);
                acc[1][j] = fmaf(a1, bb[j], acc[1][j]);
                acc[2][j] = fmaf(a2, bb[j], acc[2][j]);
                acc[3][j] = fmaf(a3, bb[j], acc[3][j]);
            }
        }
        __syncthreads();
    }

    if (MODE == 1) {
        float cmax[8];
        #pragma unroll
        for (int j = 0; j < 8; j++) {
            float bj = bias[cb + c0 + j];
            float mj = -INFINITY;
            #pragma unroll
            for (int i = 0; i < 4; i++) mj = fmaxf(mj, selu_f(acc[i][j] + bj));
            cmax[j] = mj;
        }
        float* red = As;  // reuse: [16][128]
        #pragma unroll
        for (int j = 0; j < 8; j++) red[(t >> 4) * 128 + c0 + j] = cmax[j];
        __syncthreads();
        if (t < 128) {
            float mv = -INFINITY;
            #pragma unroll
            for (int g = 0; g < 16; g++) mv = fmaxf(mv, red[g * 128 + t]);
            outf[(size_t)blockIdx.x * Nfull + cb + t] = mv;  // pmax[tile][col]
        }
    } else if (MODE == 2) {
        #pragma unroll
        for (int i = 0; i < 4; i++) {
            int row = R0 + r0 + i;
            float dv = dinv[row];
            uint4 pk;
            unsigned int* pp = (unsigned int*)&pk;
            #pragma unroll
            for (int jj = 0; jj < 4; jj++) {
                float v0 = dv * selu_f(acc[i][2 * jj + 0] + bias[cb + c0 + 2 * jj + 0]);
                float v1 = dv * selu_f(acc[i][2 * jj + 1] + bias[cb + c0 + 2 * jj + 1]);
                pp[jj] = (unsigned int)f2bf(v0) | ((unsigned int)f2bf(v1) << 16);
            }
            *(uint4*)&outh[(size_t)row * Nfull + cb + c0] = pk;
        }
    } else {
        #pragma unroll
        for (int i = 0; i < 4; i++) {
            float4 o0, o1;
            o0.x = selu_f(acc[i][0] + bias[cb + c0 + 0]);
            o0.y = selu_f(acc[i][1] + bias[cb + c0 + 1]);
            o0.z = selu_f(acc[i][2] + bias[cb + c0 + 2]);
            o0.w = selu_f(acc[i][3] + bias[cb + c0 + 3]);
            o1.x = selu_f(acc[i][4] + bias[cb + c0 + 4]);
            o1.y = selu_f(acc[i][5] + bias[cb + c0 + 5]);
            o1.z = selu_f(acc[i][6] + bias[cb + c0 + 6]);
            o1.w = selu_f(acc[i][7] + bias[cb + c0 + 7]);
            *(float4*)&outf[(size_t)(R0 + r0 + i) * Nfull + cb + c0] = o0;
            *(float4*)&outf[(size_t)(R0 + r0 + i) * Nfull + cb + c0 + 4] = o1;
        }
    }
}

// ---------------------------------------------------------------------------
// reduce pmax tiles (64 per batch) -> m[b][512]
// ---------------------------------------------------------------------------
__global__ void maxreduce_kernel(const float* __restrict__ pmax, float* __restrict__ m,
                                 int total) {
    int idx = blockIdx.x * blockDim.x + threadIdx.x;  // b*512 + c
    if (idx >= total) return;
    int b = idx >> 9;
    int c = idx & 511;
    const float* p = pmax + (size_t)(b * 64) * 512 + c;
    float v = -INFINITY;
    for (int tIdx = 0; tIdx < 64; tIdx++) v = fmaxf(v, p[tIdx * 512]);
    m[idx] = v;
}

// ---------------------------------------------------------------------------
// lat = selu(m @ w_e2 + b_e2); latw1 = lat @ w_d1[:512] + b_d1;
// latw2 = lat @ w_d2[:512] + b_d2.  One block per batch.
// ---------------------------------------------------------------------------
__global__ __launch_bounds__(256) void lat_kernel(
    const float* __restrict__ m, const float* __restrict__ w_e2,
    const float* __restrict__ b_e2, const float* __restrict__ w_d1,
    const float* __restrict__ b_d1, const float* __restrict__ w_d2,
    const float* __restrict__ b_d2, float* __restrict__ latw1,
    float* __restrict__ latw2) {
    int b = blockIdx.x;
    int t = threadIdx.x;
    __shared__ float ml[512], ll[512];
    __shared__ float red[6][256];
    ml[t] = m[b * 512 + t];
    ml[t + 256] = m[b * 512 + t + 256];
    __syncthreads();
    for (int cc = 0; cc < 2; cc++) {
        int c = t + cc * 256;
        float acc = b_e2[c];
        for (int k = 0; k < 512; k++) acc = fmaf(ml[k], w_e2[k * 512 + c], acc);
        ll[c] = selu_f(acc);
    }
    __syncthreads();
    float p[6] = {0.f, 0.f, 0.f, 0.f, 0.f, 0.f};
    for (int k = t; k < 512; k += 256) {
        float lv = ll[k];
        #pragma unroll
        for (int j = 0; j < 3; j++) {
            p[j]     = fmaf(lv, w_d1[k * 3 + j], p[j]);
            p[3 + j] = fmaf(lv, w_d2[k * 3 + j], p[3 + j]);
        }
    }
    #pragma unroll
    for (int j = 0; j < 6; j++) red[j][t] = p[j];
    __syncthreads();
    for (int s = 128; s > 0; s >>= 1) {
        if (t < s) {
            #pragma unroll
            for (int j = 0; j < 6; j++) red[j][t] += red[j][t + s];
        }
        __syncthreads();
    }
    if (t < 3) {
        latw1[b * 3 + t] = red[t][0] + b_d1[t];
        latw2[b * 3 + t] = red[3 + t][0] + b_d2[t];
    }
}

// ---------------------------------------------------------------------------
// decoder: per point, grid coords + two 3-wide folds
// ---------------------------------------------------------------------------
__global__ void decode_kernel(const float* __restrict__ latw1, const float* __restrict__ latw2,
                              const float* __restrict__ w_d1, const float* __restrict__ w_d2,
                              float* __restrict__ out, int total) {
    int p = blockIdx.x * blockDim.x + threadIdx.x;
    if (p >= total) return;
    int b = p >> 12;
    int n = p & 4095;
    int i = n / 46;
    int j = n - i * 46;
    float y0 = fmaf((float)i, 119.f / 90.f, 1.f);
    float y1 = fmaf((float)j, 59.f / 45.f, 1.f);
    float k0 = selu_f(latw1[b * 3 + 0] + y0 * w_d1[1536 + 0] + y1 * w_d1[1539 + 0]);
    float k1 = selu_f(latw1[b * 3 + 1] + y0 * w_d1[1536 + 1] + y1 * w_d1[1539 + 1]);
    float k2 = selu_f(latw1[b * 3 + 2] + y0 * w_d1[1536 + 2] + y1 * w_d1[1539 + 2]);
    float o0 = selu_f(latw2[b * 3 + 0] + k0 * w_d2[1536 + 0] + k1 * w_d2[1539 + 0] + k2 * w_d2[1542 + 0]);
    float o1 = selu_f(latw2[b * 3 + 1] + k0 * w_d2[1536 + 1] + k1 * w_d2[1539 + 1] + k2 * w_d2[1542 + 1]);
    float o2 = selu_f(latw2[b * 3 + 2] + k0 * w_d2[1536 + 2] + k1 * w_d2[1539 + 2] + k2 * w_d2[1542 + 2]);
    out[(size_t)p * 3 + 0] = o0;
    out[(size_t)p * 3 + 1] = o1;
    out[(size_t)p * 3 + 2] = o2;
}

// ---------------------------------------------------------------------------
extern "C" void kernel_launch(void* const* d_in, const int* in_sizes, int n_in,
                              void* d_out, int out_size, void* d_ws, size_t ws_size,
                              hipStream_t stream) {
    const float* x    = (const float*)d_in[0];
    const int*   knn  = (const int*)d_in[1];
    const float* w_e1 = (const float*)d_in[2];
    const float* b_e1 = (const float*)d_in[3];
    const float* w_g1 = (const float*)d_in[4];
    const float* b_g1 = (const float*)d_in[5];
    const float* w_g2 = (const float*)d_in[6];
    const float* b_g2 = (const float*)d_in[7];
    const float* w_e2 = (const float*)d_in[8];
    const float* b_e2 = (const float*)d_in[9];
    const float* w_d1 = (const float*)d_in[10];
    const float* b_d1 = (const float*)d_in[11];
    const float* w_d2 = (const float*)d_in[12];
    const float* b_d2 = (const float*)d_in[13];
    float* out = (float*)d_out;

    const int BN = in_sizes[0] / 3;   // 32768
    const int E  = in_sizes[1] / 2;   // 524288
    const int Bb = BN / 4096;         // 8
    const int* src = knn;
    const int* dst = knn + E;

    size_t off = 0;
    auto alloc = [&](size_t bytes) -> void* {
        void* p = (char*)d_ws + off;
        off += (bytes + 255) & ~(size_t)255;
        return p;
    };
    unsigned short* hs1 = (unsigned short*)alloc((size_t)BN * 64 * 2);
    unsigned short* hs2 = (unsigned short*)alloc((size_t)BN * 128 * 2);
    float* a1     = (float*)alloc((size_t)BN * 64 * 4);
    float* a2     = (float*)alloc((size_t)BN * 128 * 4);
    float* pmax   = (float*)alloc((size_t)(BN / 64) * 512 * 4);
    float* m      = (float*)alloc((size_t)Bb * 512 * 4);
    float* latw1  = (float*)alloc((size_t)Bb * 3 * 4);
    float* latw2  = (float*)alloc((size_t)Bb * 3 * 4);
    float* dinv   = (float*)alloc((size_t)BN * 4);
    int*   cnt    = (int*)alloc((size_t)BN * 4);
    int*   cursor = (int*)alloc((size_t)BN * 4);
    int*   indptr = (int*)alloc((size_t)(BN + 1) * 4);
    int*   ssrc   = (int*)alloc((size_t)E * 4);
    (void)ws_size;

    // graph prep
    zero2_kernel<<<(BN + 255) / 256, 256, 0, stream>>>(cnt, cursor, BN);
    count_kernel<<<(E + 255) / 256, 256, 0, stream>>>(dst, cnt, E);
    scan_kernel<<<1, 1024, 0, stream>>>(cnt, indptr, BN);
    dinv_kernel<<<(BN + 255) / 256, 256, 0, stream>>>(cnt, dinv, BN);
    scatter_kernel<<<(E + 255) / 256, 256, 0, stream>>>(src, dst, indptr, cursor, ssrc, E);

    // encoder (writes dinv-prescaled bf16 hs1)
    cov_enc_kernel<<<(BN + 255) / 256, 256, 0, stream>>>(x, w_e1, b_e1, dinv, hs1, BN);

    // GCN1: aggregate(64, bf16 gather) -> gemm 64x128, epilogue writes bf16 hs2
    agg_kernel<64><<<BN / 8, 256, 0, stream>>>(hs1, dinv, indptr, ssrc, a1, BN);
    gemm_kernel<64, 2><<<dim3(BN / 64, 1), 256, 0, stream>>>(a1, w_g1, b_g1, nullptr, hs2, dinv, 128);

    // GCN2: aggregate(128, bf16 gather) -> gemm 128x512 + selu + fused column-max
    agg_kernel<128><<<BN / 4, 256, 0, stream>>>(hs2, dinv, indptr, ssrc, a2, BN);
    gemm_kernel<128, 1><<<dim3(BN / 64, 4), 256, 0, stream>>>(a2, w_g2, b_g2, pmax, nullptr, nullptr, 512);

    // max-pool finalize + latent + per-batch decoder coefficients
    maxreduce_kernel<<<(Bb * 512 + 255) / 256, 256, 0, stream>>>(pmax, m, Bb * 512);
    lat_kernel<<<Bb, 256, 0, stream>>>(m, w_e2, b_e2, w_d1, b_d1, w_d2, b_d2, latw1, latw2);

    // decoder
    decode_kernel<<<(BN + 255) / 256, 256, 0, stream>>>(latw1, latw2, w_d1, w_d2, out, BN);
}

// Round 3
// 279.183 us; speedup vs baseline: 1.5642x; 1.2064x over previous
//
#include <hip/hip_runtime.h>
#include <math.h>

#define SELU_SCALE 1.0507009873554804934193349852946f
#define SELU_ALPHA 1.6732632423543772848170429916717f

typedef short bf16x8 __attribute__((ext_vector_type(8)));
typedef float f32x4 __attribute__((ext_vector_type(4)));

__device__ __forceinline__ float selu_f(float x) {
    return SELU_SCALE * (x > 0.f ? x : SELU_ALPHA * expm1f(x));
}

__device__ __forceinline__ unsigned short f2bf(float f) {
    unsigned int u = __float_as_uint(f);
    u += 0x7FFF + ((u >> 16) & 1);  // round-to-nearest-even
    return (unsigned short)(u >> 16);
}
__device__ __forceinline__ float bflo(unsigned int u) { return __uint_as_float(u << 16); }
__device__ __forceinline__ float bfhi(unsigned int u) { return __uint_as_float(u & 0xFFFF0000u); }

// ---------------------------------------------------------------------------
// K1: local covariance (window 25, divisor 23) + [x,cov] @ w_e1 + b_e1, selu,
// prescaled by dinv[p], stored bf16.  One thread per point.
// ---------------------------------------------------------------------------
__global__ __launch_bounds__(256) void cov_enc_kernel(
    const float* __restrict__ x, const float* __restrict__ w_e1,
    const float* __restrict__ b_e1, const float* __restrict__ dinv,
    unsigned short* __restrict__ hs1, int BN) {
    __shared__ float Wl[12 * 64];
    __shared__ float Bl[64];
    int t = threadIdx.x;
    for (int i = t; i < 768; i += 256) Wl[i] = w_e1[i];
    if (t < 64) Bl[t] = b_e1[t];
    __syncthreads();
    int p = blockIdx.x * 256 + t;
    if (p >= BN) return;
    int n = p & 4095;
    const float* xb = x + (size_t)(p - n) * 3;  // batch base
    int lo = n - 12 < 0 ? 0 : n - 12;
    int hi = n + 12 > 4095 ? 4095 : n + 12;
    float sx = 0.f, sy = 0.f, sz = 0.f;
    for (int idx = lo; idx <= hi; idx++) {
        sx += xb[idx * 3 + 0];
        sy += xb[idx * 3 + 1];
        sz += xb[idx * 3 + 2];
    }
    float cntf = (float)(hi - lo + 1);
    float mx = sx / cntf, my = sy / cntf, mz = sz / cntf;
    float c00 = 0.f, c01 = 0.f, c02 = 0.f, c11 = 0.f, c12 = 0.f, c22 = 0.f;
    for (int idx = lo; idx <= hi; idx++) {
        float dx = xb[idx * 3 + 0] - mx;
        float dy = xb[idx * 3 + 1] - my;
        float dz = xb[idx * 3 + 2] - mz;
        c00 = fmaf(dx, dx, c00); c01 = fmaf(dx, dy, c01); c02 = fmaf(dx, dz, c02);
        c11 = fmaf(dy, dy, c11); c12 = fmaf(dy, dz, c12); c22 = fmaf(dz, dz, c22);
    }
    const float inv23 = 1.f / 23.f;
    float feat[12];
    feat[0] = xb[n * 3 + 0]; feat[1] = xb[n * 3 + 1]; feat[2] = xb[n * 3 + 2];
    feat[3] = c00 * inv23; feat[4] = c01 * inv23; feat[5]  = c02 * inv23;
    feat[6] = c01 * inv23; feat[7] = c11 * inv23; feat[8]  = c12 * inv23;
    feat[9] = c02 * inv23; feat[10] = c12 * inv23; feat[11] = c22 * inv23;
    float dv = dinv[p];
    unsigned int* hp = (unsigned int*)(hs1 + (size_t)p * 64);
    for (int c = 0; c < 64; c += 2) {
        float a0 = Bl[c], a1 = Bl[c + 1];
        #pragma unroll
        for (int i = 0; i < 12; i++) {
            a0 = fmaf(feat[i], Wl[i * 64 + c], a0);
            a1 = fmaf(feat[i], Wl[i * 64 + c + 1], a1);
        }
        unsigned int pk = (unsigned int)f2bf(dv * selu_f(a0)) |
                          ((unsigned int)f2bf(dv * selu_f(a1)) << 16);
        hp[c >> 1] = pk;
    }
}

// ---------------------------------------------------------------------------
// Graph prep: zero, count, scan, dinv, scatter (CSR by dst)
// ---------------------------------------------------------------------------
__global__ void zero2_kernel(int* __restrict__ a, int* __restrict__ b, int n) {
    int i = blockIdx.x * blockDim.x + threadIdx.x;
    if (i < n) { a[i] = 0; b[i] = 0; }
}

__global__ void count_kernel(const int* __restrict__ dst, int* __restrict__ cnt, int E) {
    int e = blockIdx.x * blockDim.x + threadIdx.x;
    if (e < E) atomicAdd(&cnt[dst[e]], 1);
}

__global__ __launch_bounds__(1024) void scan_kernel(
    const int* __restrict__ cnt, int* __restrict__ indptr, int n) {
    // n == 32768, one block of 1024 threads, 32 elems per thread
    __shared__ int sums[1024];
    int t = threadIdx.x;
    int base = t * 32;
    int local[32];
    int s = 0;
    #pragma unroll
    for (int i = 0; i < 32; i++) { local[i] = s; s += cnt[base + i]; }
    sums[t] = s;
    __syncthreads();
    for (int off = 1; off < 1024; off <<= 1) {
        int v = (t >= off) ? sums[t - off] : 0;
        __syncthreads();
        sums[t] += v;
        __syncthreads();
    }
    int off = sums[t] - s;  // exclusive prefix for this chunk
    #pragma unroll
    for (int i = 0; i < 32; i++) indptr[base + i] = off + local[i];
    if (t == 1023) indptr[n] = sums[1023];
}

__global__ void dinv_kernel(const int* __restrict__ cnt, float* __restrict__ dinv, int n) {
    int i = blockIdx.x * blockDim.x + threadIdx.x;
    if (i < n) dinv[i] = rsqrtf((float)(cnt[i] + 1));  // +1 self-loop
}

__global__ void scatter_kernel(const int* __restrict__ src, const int* __restrict__ dst,
                               const int* __restrict__ indptr, int* __restrict__ cursor,
                               int* __restrict__ ssrc, int E) {
    int e = blockIdx.x * blockDim.x + threadIdx.x;
    if (e < E) {
        int d = dst[e];
        int pos = atomicAdd(&cursor[d], 1);
        ssrc[indptr[d] + pos] = src[e];
    }
}

// ---------------------------------------------------------------------------
// Aggregation: out[d] = dinv[d] * ( hs[d] + sum_{s in N(d)} hs[s] )  where
// hs = dinv .* h (prescaled bf16).  2 channels per thread (uint gather).
// Output written as bf16 pairs (feeds MFMA GEMM).
// ---------------------------------------------------------------------------
template <int C>
__global__ __launch_bounds__(256) void agg_kernel(
    const unsigned short* __restrict__ hs, const float* __restrict__ dinv,
    const int* __restrict__ indptr, const int* __restrict__ ssrc,
    unsigned short* __restrict__ out, int n_nodes) {
    constexpr int TPN = C / 2;  // threads per node
    int node = blockIdx.x * (256 / TPN) + threadIdx.x / TPN;
    int cp = threadIdx.x % TPN;  // channel pair
    if (node >= n_nodes) return;
    const unsigned int* hsp = (const unsigned int*)hs;
    unsigned int u = hsp[(size_t)node * TPN + cp];
    float a0 = bflo(u), a1 = bfhi(u);
    int beg = indptr[node], end = indptr[node + 1];
    int j = beg;
    for (; j + 8 <= end; j += 8) {
        int s[8];
        #pragma unroll
        for (int q = 0; q < 8; q++) s[q] = ssrc[j + q];
        unsigned int v[8];
        #pragma unroll
        for (int q = 0; q < 8; q++) v[q] = hsp[(size_t)s[q] * TPN + cp];
        #pragma unroll
        for (int q = 0; q < 8; q++) { a0 += bflo(v[q]); a1 += bfhi(v[q]); }
    }
    for (; j < end; j++) {
        unsigned int v = hsp[(size_t)ssrc[j] * TPN + cp];
        a0 += bflo(v); a1 += bfhi(v);
    }
    float dv = dinv[node];
    unsigned int pk = (unsigned int)f2bf(a0 * dv) | ((unsigned int)f2bf(a1 * dv) << 16);
    ((unsigned int*)out)[(size_t)node * TPN + cp] = pk;
}

// ---------------------------------------------------------------------------
// Pack W [K][N] f32 -> bf16 B-fragments for mfma_f32_16x16x32_bf16.
// Fragment f = nt*(K/32)+ks holds lane l element j = W[ks*32+(l>>4)*8+j][nt*16+(l&15)].
// One block (64 threads) per fragment; each thread writes one 16B lane slot.
// ---------------------------------------------------------------------------
__global__ void packW_kernel(const float* __restrict__ W, unsigned short* __restrict__ Wp,
                             int K, int N) {
    int f = blockIdx.x;
    int l = threadIdx.x;  // 0..63
    int KS = K / 32;
    int nt = f / KS, ks = f % KS;
    int ncol = nt * 16 + (l & 15);
    int k0 = ks * 32 + (l >> 4) * 8;
    unsigned short v[8];
    #pragma unroll
    for (int j = 0; j < 8; j++) v[j] = f2bf(W[(size_t)(k0 + j) * N + ncol]);
    *(uint4*)&Wp[((size_t)f * 64 + l) * 8] = *(uint4*)v;
}

// ---------------------------------------------------------------------------
// MFMA bf16 GEMM: out = f(A[M,KTOT]bf16 @ W[KTOT,Nfull] + bias)
// Block: 256 thr (4 waves), tile 128 rows x 128 cols. Wave w: rows w*32..w*32+31.
// MODE 1: per-tile column max of selu(...)        -> pmax[blockIdx.x][Nfull]
// MODE 2: bf16 rows dinv[row]*selu(...)           -> outh
// ---------------------------------------------------------------------------
template <int KTOT, int MODE>
__global__ __launch_bounds__(256) void mfma_gemm_kernel(
    const unsigned short* __restrict__ A, const unsigned short* __restrict__ Wp,
    const float* __restrict__ bias, float* __restrict__ pmax,
    unsigned short* __restrict__ outh, const float* __restrict__ dinv, int Nfull) {
    constexpr int KS = KTOT / 32;      // k-steps
    constexpr int LDA = KTOT + 8;      // padded LDS row stride (bf16 units)
    constexpr int CPR = KTOT / 8;      // 16B chunks per row
    __shared__ unsigned short As[128 * LDA];
    int t = threadIdx.x;
    int wave = t >> 6, l = t & 63;
    int ml = l & 15, q = l >> 4;
    int R0 = blockIdx.x * 128;
    int cb = blockIdx.y * 128;

    // stage A tile (128 rows x KTOT) into padded LDS
    for (int c = t; c < 128 * CPR; c += 256) {
        int row = c / CPR, off = c % CPR;
        *(uint4*)&As[row * LDA + off * 8] =
            *(const uint4*)&A[(size_t)(R0 + row) * KTOT + off * 8];
    }
    __syncthreads();

    f32x4 acc[2][8];
    #pragma unroll
    for (int mf = 0; mf < 2; mf++)
        #pragma unroll
        for (int nf = 0; nf < 8; nf++) acc[mf][nf] = (f32x4){0.f, 0.f, 0.f, 0.f};

    const bf16x8* wp8 = (const bf16x8*)Wp;
    int wr = wave * 32;
    #pragma unroll
    for (int ks = 0; ks < KS; ks++) {
        bf16x8 af[2];
        #pragma unroll
        for (int mf = 0; mf < 2; mf++)
            af[mf] = *(const bf16x8*)&As[(wr + mf * 16 + ml) * LDA + ks * 32 + q * 8];
        bf16x8 bf[8];
        #pragma unroll
        for (int nf = 0; nf < 8; nf++)
            bf[nf] = wp8[(size_t)(((cb >> 4) + nf) * KS + ks) * 64 + l];
        #pragma unroll
        for (int mf = 0; mf < 2; mf++)
            #pragma unroll
            for (int nf = 0; nf < 8; nf++)
                acc[mf][nf] = __builtin_amdgcn_mfma_f32_16x16x32_bf16(
                    af[mf], bf[nf], acc[mf][nf], 0, 0, 0);
    }

    if (MODE == 1) {
        // selu + column max; C/D layout: col = ml, row = q*4 + r
        float cmax[8];
        #pragma unroll
        for (int nf = 0; nf < 8; nf++) {
            float bj = bias[cb + nf * 16 + ml];
            float v = -INFINITY;
            #pragma unroll
            for (int mf = 0; mf < 2; mf++)
                #pragma unroll
                for (int r = 0; r < 4; r++)
                    v = fmaxf(v, selu_f(acc[mf][nf][r] + bj));
            v = fmaxf(v, __shfl_xor(v, 16, 64));
            v = fmaxf(v, __shfl_xor(v, 32, 64));
            cmax[nf] = v;
        }
        __syncthreads();  // before reusing As as f32 scratch
        float* redf = (float*)As;  // [4 waves][128 cols]
        if (ml == l) {  // lanes 0..15
            #pragma unroll
            for (int nf = 0; nf < 8; nf++) redf[wave * 128 + nf * 16 + l] = cmax[nf];
        }
        __syncthreads();
        if (t < 128) {
            float v = redf[t];
            v = fmaxf(v, redf[128 + t]);
            v = fmaxf(v, redf[256 + t]);
            v = fmaxf(v, redf[384 + t]);
            pmax[(size_t)blockIdx.x * Nfull + cb + t] = v;
        }
    } else {
        // dinv[row]*selu(...) -> bf16
        float bj[8];
        #pragma unroll
        for (int nf = 0; nf < 8; nf++) bj[nf] = bias[cb + nf * 16 + ml];
        #pragma unroll
        for (int mf = 0; mf < 2; mf++) {
            #pragma unroll
            for (int r = 0; r < 4; r++) {
                int row = R0 + wr + mf * 16 + q * 4 + r;
                float dv = dinv[row];
                #pragma unroll
                for (int nf = 0; nf < 8; nf++) {
                    float v = dv * selu_f(acc[mf][nf][r] + bj[nf]);
                    outh[(size_t)row * Nfull + cb + nf * 16 + ml] = f2bf(v);
                }
            }
        }
    }
}

// ---------------------------------------------------------------------------
// reduce pmax tiles (32 per batch, 128-row tiles) -> m[b][512]
// ---------------------------------------------------------------------------
__global__ void maxreduce_kernel(const float* __restrict__ pmax, float* __restrict__ m,
                                 int total) {
    int idx = blockIdx.x * blockDim.x + threadIdx.x;  // b*512 + c
    if (idx >= total) return;
    int b = idx >> 9;
    int c = idx & 511;
    const float* p = pmax + (size_t)(b * 32) * 512 + c;
    float v = -INFINITY;
    for (int tIdx = 0; tIdx < 32; tIdx++) v = fmaxf(v, p[tIdx * 512]);
    m[idx] = v;
}

// ---------------------------------------------------------------------------
// lat = selu(m @ w_e2 + b_e2); latw1 = lat @ w_d1[:512] + b_d1;
// latw2 = lat @ w_d2[:512] + b_d2.  One block per batch.
// ---------------------------------------------------------------------------
__global__ __launch_bounds__(256) void lat_kernel(
    const float* __restrict__ m, const float* __restrict__ w_e2,
    const float* __restrict__ b_e2, const float* __restrict__ w_d1,
    const float* __restrict__ b_d1, const float* __restrict__ w_d2,
    const float* __restrict__ b_d2, float* __restrict__ latw1,
    float* __restrict__ latw2) {
    int b = blockIdx.x;
    int t = threadIdx.x;
    __shared__ float ml[512], ll[512];
    __shared__ float red[6][256];
    ml[t] = m[b * 512 + t];
    ml[t + 256] = m[b * 512 + t + 256];
    __syncthreads();
    for (int cc = 0; cc < 2; cc++) {
        int c = t + cc * 256;
        float acc = b_e2[c];
        for (int k = 0; k < 512; k++) acc = fmaf(ml[k], w_e2[k * 512 + c], acc);
        ll[c] = selu_f(acc);
    }
    __syncthreads();
    float p[6] = {0.f, 0.f, 0.f, 0.f, 0.f, 0.f};
    for (int k = t; k < 512; k += 256) {
        float lv = ll[k];
        #pragma unroll
        for (int j = 0; j < 3; j++) {
            p[j]     = fmaf(lv, w_d1[k * 3 + j], p[j]);
            p[3 + j] = fmaf(lv, w_d2[k * 3 + j], p[3 + j]);
        }
    }
    #pragma unroll
    for (int j = 0; j < 6; j++) red[j][t] = p[j];
    __syncthreads();
    for (int s = 128; s > 0; s >>= 1) {
        if (t < s) {
            #pragma unroll
            for (int j = 0; j < 6; j++) red[j][t] += red[j][t + s];
        }
        __syncthreads();
    }
    if (t < 3) {
        latw1[b * 3 + t] = red[t][0] + b_d1[t];
        latw2[b * 3 + t] = red[3 + t][0] + b_d2[t];
    }
}

// ---------------------------------------------------------------------------
// decoder: per point, grid coords + two 3-wide folds
// ---------------------------------------------------------------------------
__global__ void decode_kernel(const float* __restrict__ latw1, const float* __restrict__ latw2,
                              const float* __restrict__ w_d1, const float* __restrict__ w_d2,
                              float* __restrict__ out, int total) {
    int p = blockIdx.x * blockDim.x + threadIdx.x;
    if (p >= total) return;
    int b = p >> 12;
    int n = p & 4095;
    int i = n / 46;
    int j = n - i * 46;
    float y0 = fmaf((float)i, 119.f / 90.f, 1.f);
    float y1 = fmaf((float)j, 59.f / 45.f, 1.f);
    float k0 = selu_f(latw1[b * 3 + 0] + y0 * w_d1[1536 + 0] + y1 * w_d1[1539 + 0]);
    float k1 = selu_f(latw1[b * 3 + 1] + y0 * w_d1[1536 + 1] + y1 * w_d1[1539 + 1]);
    float k2 = selu_f(latw1[b * 3 + 2] + y0 * w_d1[1536 + 2] + y1 * w_d1[1539 + 2]);
    float o0 = selu_f(latw2[b * 3 + 0] + k0 * w_d2[1536 + 0] + k1 * w_d2[1539 + 0] + k2 * w_d2[1542 + 0]);
    float o1 = selu_f(latw2[b * 3 + 1] + k0 * w_d2[1536 + 1] + k1 * w_d2[1539 + 1] + k2 * w_d2[1542 + 1]);
    float o2 = selu_f(latw2[b * 3 + 2] + k0 * w_d2[1536 + 2] + k1 * w_d2[1539 + 2] + k2 * w_d2[1542 + 2]);
    out[(size_t)p * 3 + 0] = o0;
    out[(size_t)p * 3 + 1] = o1;
    out[(size_t)p * 3 + 2] = o2;
}

// ---------------------------------------------------------------------------
extern "C" void kernel_launch(void* const* d_in, const int* in_sizes, int n_in,
                              void* d_out, int out_size, void* d_ws, size_t ws_size,
                              hipStream_t stream) {
    const float* x    = (const float*)d_in[0];
    const int*   knn  = (const int*)d_in[1];
    const float* w_e1 = (const float*)d_in[2];
    const float* b_e1 = (const float*)d_in[3];
    const float* w_g1 = (const float*)d_in[4];
    const float* b_g1 = (const float*)d_in[5];
    const float* w_g2 = (const float*)d_in[6];
    const float* b_g2 = (const float*)d_in[7];
    const float* w_e2 = (const float*)d_in[8];
    const float* b_e2 = (const float*)d_in[9];
    const float* w_d1 = (const float*)d_in[10];
    const float* b_d1 = (const float*)d_in[11];
    const float* w_d2 = (const float*)d_in[12];
    const float* b_d2 = (const float*)d_in[13];
    float* out = (float*)d_out;

    const int BN = in_sizes[0] / 3;   // 32768
    const int E  = in_sizes[1] / 2;   // 524288
    const int Bb = BN / 4096;         // 8
    const int* src = knn;
    const int* dst = knn + E;

    size_t off = 0;
    auto alloc = [&](size_t bytes) -> void* {
        void* p = (char*)d_ws + off;
        off += (bytes + 255) & ~(size_t)255;
        return p;
    };
    unsigned short* hs1 = (unsigned short*)alloc((size_t)BN * 64 * 2);
    unsigned short* hs2 = (unsigned short*)alloc((size_t)BN * 128 * 2);
    unsigned short* a1  = (unsigned short*)alloc((size_t)BN * 64 * 2);
    unsigned short* a2  = (unsigned short*)alloc((size_t)BN * 128 * 2);
    unsigned short* Wp1 = (unsigned short*)alloc((size_t)16 * 64 * 8 * 2);
    unsigned short* Wp2 = (unsigned short*)alloc((size_t)128 * 64 * 8 * 2);
    float* pmax   = (float*)alloc((size_t)(BN / 128) * 512 * 4);
    float* m      = (float*)alloc((size_t)Bb * 512 * 4);
    float* latw1  = (float*)alloc((size_t)Bb * 3 * 4);
    float* latw2  = (float*)alloc((size_t)Bb * 3 * 4);
    float* dinv   = (float*)alloc((size_t)BN * 4);
    int*   cnt    = (int*)alloc((size_t)BN * 4);
    int*   cursor = (int*)alloc((size_t)BN * 4);
    int*   indptr = (int*)alloc((size_t)(BN + 1) * 4);
    int*   ssrc   = (int*)alloc((size_t)E * 4);
    (void)ws_size;

    // weight packs (independent of graph)
    packW_kernel<<<16, 64, 0, stream>>>(w_g1, Wp1, 64, 128);
    packW_kernel<<<128, 64, 0, stream>>>(w_g2, Wp2, 128, 512);

    // graph prep
    zero2_kernel<<<(BN + 255) / 256, 256, 0, stream>>>(cnt, cursor, BN);
    count_kernel<<<(E + 255) / 256, 256, 0, stream>>>(dst, cnt, E);
    scan_kernel<<<1, 1024, 0, stream>>>(cnt, indptr, BN);
    dinv_kernel<<<(BN + 255) / 256, 256, 0, stream>>>(cnt, dinv, BN);
    scatter_kernel<<<(E + 255) / 256, 256, 0, stream>>>(src, dst, indptr, cursor, ssrc, E);

    // encoder (writes dinv-prescaled bf16 hs1)
    cov_enc_kernel<<<(BN + 255) / 256, 256, 0, stream>>>(x, w_e1, b_e1, dinv, hs1, BN);

    // GCN1: aggregate(64, bf16) -> MFMA gemm 64x128, epilogue writes bf16 hs2 (dinv-prescaled)
    agg_kernel<64><<<BN / 8, 256, 0, stream>>>(hs1, dinv, indptr, ssrc, a1, BN);
    mfma_gemm_kernel<64, 2><<<dim3(BN / 128, 1), 256, 0, stream>>>(
        a1, Wp1, b_g1, nullptr, hs2, dinv, 128);

    // GCN2: aggregate(128, bf16) -> MFMA gemm 128x512 + selu + fused column-max
    agg_kernel<128><<<BN / 4, 256, 0, stream>>>(hs2, dinv, indptr, ssrc, a2, BN);
    mfma_gemm_kernel<128, 1><<<dim3(BN / 128, 4), 256, 0, stream>>>(
        a2, Wp2, b_g2, pmax, nullptr, nullptr, 512);

    // max-pool finalize + latent + per-batch decoder coefficients
    maxreduce_kernel<<<(Bb * 512 + 255) / 256, 256, 0, stream>>>(pmax, m, Bb * 512);
    lat_kernel<<<Bb, 256, 0, stream>>>(m, w_e2, b_e2, w_d1, b_d1, w_d2, b_d2, latw1, latw2);

    // decoder
    decode_kernel<<<(BN + 255) / 256, 256, 0, stream>>>(latw1, latw2, w_d1, w_d2, out, BN);
}